// Round 13
// baseline (159.992 us; speedup 1.0000x reference)
//
#include <hip/hip_runtime.h>

#define B_ 2
#define N_ 1024
#define C_ 256
#define P_ 256
#define K_ 27
#define M_ (P_ * K_)        // 6912
#define TOTKP (B_ * M_)     // 13824
#define NS 16
#define R2C 0.04f
#define QDIM 864            // 32*K_

// ---------------- ws layout (bytes) ----------------
// kp4 : float4[TOTKP]   @ 0        (221184)
// cnt : int[TOTKP]      @ 221184   (55296)
// idx : int[TOTKP*16]   @ 276480   (884736)
// F   : float[B*N*128]  @ 1161216  (1048576)
// WrT : float[864*128]  @ 2209792  (442368)   total ~2.65 MB

// prep_k blockIdx ranges
#define PREP_WRT0    256      // 108 blocks
#define PREP_BALLQ0  364      // 3456 blocks
#define PREP_NBLK    3820

// ---------- kernel 1: fused prep = fpre + WrT transpose + ball query ----------
__global__ __launch_bounds__(256) void prep_k(
    const float* __restrict__ sf, const float* __restrict__ W1,
    const float* __restrict__ b1, const float* __restrict__ Wr,
    const float* __restrict__ seed_xyz, const float* __restrict__ boxes,
    const float* __restrict__ origins, const float* __restrict__ heading,
    float* __restrict__ F, float* __restrict__ WrT,
    float4* __restrict__ kp4, int* __restrict__ cntw, int* __restrict__ idxw)
{
    __shared__ __align__(16) float ssf[C_ * 8];
    int tid = threadIdx.x;
    int bid = blockIdx.x;

    if (bid < PREP_WRT0) {
        // ---- task A: F'[b,n,j] = b1[j] + sum_c sf[b,c,n]*W1[3+c,j] ----
        int b = bid >> 7;
        int n0 = (bid & 127) * 8;
        for (int e = tid; e < C_ * 8; e += 256) {
            int c = e >> 3, i = e & 7;
            ssf[e] = sf[(b * C_ + c) * N_ + n0 + i];
        }
        __syncthreads();
        int j = tid & 127;
        int h = tid >> 7;               // 4-seed half
        float acc[4];
        float bj = b1[j];
#pragma unroll
        for (int i = 0; i < 4; i++) acc[i] = bj;
#pragma unroll 8
        for (int c = 0; c < C_; ++c) {
            float w = W1[(3 + c) * 128 + j];
            float4 s = *(const float4*)&ssf[c * 8 + h * 4];
            acc[0] = fmaf(s.x, w, acc[0]);
            acc[1] = fmaf(s.y, w, acc[1]);
            acc[2] = fmaf(s.z, w, acc[2]);
            acc[3] = fmaf(s.w, w, acc[3]);
        }
#pragma unroll
        for (int i = 0; i < 4; i++)
            F[(b * N_ + n0 + h * 4 + i) * 128 + j] = acc[i];
    } else if (bid < PREP_BALLQ0) {
        // ---- task B: WrT[q][j] = Wr[j][q], float4 reads ----
        int e4 = (bid - PREP_WRT0) * 256 + tid;       // < 27648
        int j = e4 / 216, qq = e4 - j * 216;
        float4 v = ((const float4*)(Wr + j * QDIM))[qq];
        int q0 = qq * 4;
        WrT[(q0 + 0) * 128 + j] = v.x;
        WrT[(q0 + 1) * 128 + j] = v.y;
        WrT[(q0 + 2) * 128 + j] = v.z;
        WrT[(q0 + 3) * 128 + j] = v.w;
    } else {
        // ---- task C: keypoints + ball query (wave per keypoint) ----
        int wid = tid >> 6, lane = tid & 63;
        int kpg = (bid - PREP_BALLQ0) * 4 + wid;
        int b = kpg / M_;
        int m = kpg - b * M_;
        int p = m / K_, a = m - p * K_;

        const float* bx = boxes + (b * P_ + p) * 6;
        const float* og = origins + (b * P_ + p) * 3;
        float th = heading[b * P_ + p];
        float di = (float)(a / 9), dj = (float)((a / 3) % 3), dk = (float)(a % 3);
        float s0 = __fadd_rn(bx[0], bx[3]);
        float s1 = __fadd_rn(bx[1], bx[4]);
        float s2 = __fadd_rn(bx[2], bx[5]);
        float lx = __fsub_rn(__fmul_rn(__fdiv_rn(__fadd_rn(di, 0.5f), 3.0f), s0), bx[0]);
        float ly = __fsub_rn(__fmul_rn(__fdiv_rn(__fadd_rn(dj, 0.5f), 3.0f), s1), bx[1]);
        float lz = __fsub_rn(__fmul_rn(__fdiv_rn(__fadd_rn(dk, 0.5f), 3.0f), s2), bx[2]);
        float ct = cosf(th), st = sinf(th);
        float kx = __fadd_rn(__fadd_rn(__fmul_rn(lx, ct), __fmul_rn(ly, st)), og[0]);
        float ky = __fadd_rn(__fadd_rn(__fmul_rn(lx, -st), __fmul_rn(ly, ct)), og[1]);
        float kz = __fadd_rn(lz, og[2]);
        if (lane == 0) kp4[kpg] = make_float4(kx, ky, kz, 0.f);
        float kk = __fadd_rn(__fadd_rn(__fmul_rn(kx, kx), __fmul_rn(ky, ky)),
                             __fmul_rn(kz, kz));

        const float* sb = seed_xyz + b * (N_ * 3) + lane * 48;
        float f[48];
#pragma unroll
        for (int q = 0; q < 12; q++)
            ((float4*)f)[q] = ((const float4*)sb)[q];

        unsigned mask = 0;
#pragma unroll
        for (int i = 0; i < 16; i++) {
            float x = f[3 * i], y = f[3 * i + 1], z = f[3 * i + 2];
            float ss = __fadd_rn(__fadd_rn(__fmul_rn(x, x), __fmul_rn(y, y)),
                                 __fmul_rn(z, z));
            float dot = __fadd_rn(__fadd_rn(__fmul_rn(kx, x), __fmul_rn(ky, y)),
                                  __fmul_rn(kz, z));
            float d2 = __fsub_rn(__fadd_rn(kk, ss), __fmul_rn(2.0f, dot));
            mask |= (d2 < R2C ? 1u : 0u) << i;
        }

        int pc = __popc(mask);
        int incl = pc;
#pragma unroll
        for (int d = 1; d < 64; d <<= 1) {
            int v = __shfl_up(incl, d);
            if (lane >= d) incl += v;
        }
        int total = __shfl(incl, 63);
        int base = incl - pc;

        int* ip = idxw + kpg * NS;
        unsigned mm = mask;
        while (mm && base < NS) {
            int i = __ffs(mm) - 1;
            mm &= mm - 1;
            ip[base++] = lane * 16 + i;
        }
        if (lane == 0) cntw[kpg] = total < NS ? total : NS;
    }
}

// ---------- kernel 2: per-box worklist MLP + atomic maxpool + GEMM ----------
// one block of 512 threads (8 waves) per (b,p) box.
__global__ __launch_bounds__(512, 4) void pf_k(
    const float* __restrict__ seed_xyz, const float* __restrict__ F,
    const float* __restrict__ W1, const float* __restrict__ b2g,
    const float* __restrict__ b3g, const float* __restrict__ W2g,
    const float* __restrict__ W3g, const float* __restrict__ WrT,
    const float* __restrict__ br, const float4* __restrict__ kp4,
    const int* __restrict__ cntw, const int* __restrict__ idxw,
    float* __restrict__ out)
{
    __shared__ __align__(16) float sW2[128 * 64];      // 32 KB
    __shared__ __align__(16) float sW3[64 * 32];       // 8 KB
    __shared__ __align__(16) float sH1[8 * 4 * 128];   // 16 KB
    __shared__ __align__(16) float sH2[8 * 4 * 64];    // 8 KB
    __shared__ __align__(16) int   ft_i[QDIM];         // 3.4 KB
    __shared__ __align__(16) int   swl[K_ * NS];       // 1.7 KB worklist (k<<16)|n
    __shared__ __align__(16) float4 skp[K_];           // keypoints
    __shared__ int scnt[K_], koff[K_], sS;
    __shared__ __align__(16) float spart[512];

    int tid = threadIdx.x;
    int wid = tid >> 6, lane = tid & 63;
    int bp = blockIdx.x;              // 0..511
    int b = bp >> 8, p = bp & 255;

    // ---- stage weights, metadata; zero ft ----
    for (int e = tid; e < 2048; e += 512)
        ((float4*)sW2)[e] = ((const float4*)W2g)[e];
    for (int e = tid; e < 512; e += 512)
        ((float4*)sW3)[e] = ((const float4*)W3g)[e];
    for (int e = tid; e < QDIM; e += 512)
        ft_i[e] = 0;
    if (tid < K_) {
        int kpg = bp * K_ + tid;
        scnt[tid] = cntw[kpg];
        skp[tid] = kp4[kpg];
    }
    __syncthreads();

    // ---- wave 0: exclusive scan of per-keypoint list counts (lc = max(cnt,1)) ----
    if (wid == 0) {
        int lc = 0;
        if (lane < K_) {
            int cc = scnt[lane];
            lc = cc > 0 ? cc : 1;
        }
        int incl = lc;
#pragma unroll
        for (int d = 1; d < 32; d <<= 1) {
            int v = __shfl_up(incl, d);
            if (lane >= d) incl += v;
        }
        if (lane < K_) koff[lane] = incl - lc;
        if (lane == K_ - 1) sS = incl;
    }
    __syncthreads();

    // ---- fill worklist ----
    if (tid < K_ * NS) {
        int k = tid >> 4, s = tid & 15;
        int cc = scnt[k];
        int lc = cc > 0 ? cc : 1;
        if (s < lc) {
            int n = (s < cc) ? idxw[(bp * K_ + k) * NS + s] : 0;
            swl[koff[k] + s] = (k << 16) | n;
        }
    }
    __syncthreads();

    int S = sS;
    int G = (S + 3) >> 2;

    // per-lane constants
    float w1x0 = W1[lane],        w1x1 = W1[lane + 64];
    float w1y0 = W1[128 + lane],  w1y1 = W1[128 + lane + 64];
    float w1z0 = W1[256 + lane],  w1z1 = W1[256 + lane + 64];
    float b2j = b2g[lane];
    float b3t = b3g[lane & 31];
    int jh = lane >> 5;
    int t = lane & 31;
    float* myH1 = sH1 + wid * 4 * 128;
    float* myH2 = sH2 + wid * 4 * 64;

    // ---- phase A: GS=4 groups over the worklist, wave-strided ----
    for (int g = wid; g < G; g += 8) {
        int kk4[4], nn[4];
        float gx[4], gy[4], gz[4];
#pragma unroll
        for (int u = 0; u < 4; u++) {
            int e = 4 * g + u; if (e >= S) e = S - 1;
            int w = swl[e];
            int k = w >> 16, n = w & 0xffff;
            kk4[u] = k; nn[u] = n;
            float4 kp = skp[k];
            const float* sp = seed_xyz + (b * N_ + n) * 3;
            gx[u] = __fdiv_rn(__fsub_rn(sp[0], kp.x), 0.2f);
            gy[u] = __fdiv_rn(__fsub_rn(sp[1], kp.y), 0.2f);
            gz[u] = __fdiv_rn(__fsub_rn(sp[2], kp.z), 0.2f);
        }
#pragma unroll
        for (int u = 0; u < 4; u++) {
            const float* fp = F + (b * N_ + nn[u]) * 128;
            float v0 = fp[lane];
            float v1 = fp[lane + 64];
            v0 = fmaf(gx[u], w1x0, fmaf(gy[u], w1y0, fmaf(gz[u], w1z0, v0)));
            v1 = fmaf(gx[u], w1x1, fmaf(gy[u], w1y1, fmaf(gz[u], w1z1, v1)));
            myH1[u * 128 + lane] = fmaxf(v0, 0.f);
            myH1[u * 128 + lane + 64] = fmaxf(v1, 0.f);
        }
        float acc[4];
#pragma unroll
        for (int u = 0; u < 4; u++) acc[u] = b2j;
#pragma unroll
        for (int cc = 0; cc < 128; cc += 4) {
            float w0 = sW2[(cc + 0) * 64 + lane];
            float w1 = sW2[(cc + 1) * 64 + lane];
            float w2 = sW2[(cc + 2) * 64 + lane];
            float w3 = sW2[(cc + 3) * 64 + lane];
#pragma unroll
            for (int u = 0; u < 4; u++) {
                float4 h = *(const float4*)&myH1[u * 128 + cc];
                acc[u] = fmaf(h.x, w0, fmaf(h.y, w1, fmaf(h.z, w2, fmaf(h.w, w3, acc[u]))));
            }
        }
#pragma unroll
        for (int u = 0; u < 4; u++) myH2[u * 64 + lane] = fmaxf(acc[u], 0.f);
        float a3[4];
#pragma unroll
        for (int u = 0; u < 4; u++) a3[u] = (jh == 0) ? b3t : 0.f;
#pragma unroll
        for (int jj = 0; jj < 32; jj += 4) {
            int j0 = jh * 32 + jj;
            float w0 = sW3[(j0 + 0) * 32 + t];
            float w1 = sW3[(j0 + 1) * 32 + t];
            float w2 = sW3[(j0 + 2) * 32 + t];
            float w3 = sW3[(j0 + 3) * 32 + t];
#pragma unroll
            for (int u = 0; u < 4; u++) {
                float4 h = *(const float4*)&myH2[u * 64 + j0];
                a3[u] = fmaf(h.x, w0, fmaf(h.y, w1, fmaf(h.z, w2, fmaf(h.w, w3, a3[u]))));
            }
        }
#pragma unroll
        for (int u = 0; u < 4; u++) {
            float v = a3[u] + __shfl_xor(a3[u], 32);
            int vi = __float_as_int(fmaxf(v, 0.f));
            if (lane < 32) atomicMax(&ft_i[t * K_ + kk4[u]], vi);
        }
    }
    __syncthreads();

    // ---- phase B: out[b,j,p] = br[j] + sum_q ft[q]*WrT[q,j]  (4-way K split) ----
    int j = tid & 127;
    int h = tid >> 7;                 // 0..3, q range [h*216, h*216+216)
    float a = 0.f;
    const int* fq = ft_i + h * 216;
    const float* wq = WrT + (h * 216) * 128 + j;
#pragma unroll 4
    for (int q = 0; q < 216; ++q)
        a = fmaf(__int_as_float(fq[q]), wq[q * 128], a);
    spart[tid] = a;
    __syncthreads();
    if (tid < 128)
        out[(b * 128 + tid) * 256 + p] =
            spart[tid] + spart[128 + tid] + spart[256 + tid] + spart[384 + tid] + br[tid];
}

extern "C" void kernel_launch(void* const* d_in, const int* in_sizes, int n_in,
                              void* d_out, int out_size, void* d_ws, size_t ws_size,
                              hipStream_t stream)
{
    const float* seed_xyz  = (const float*)d_in[0];
    const float* seed_feat = (const float*)d_in[1];
    const float* boxes     = (const float*)d_in[2];
    const float* origins   = (const float*)d_in[3];
    const float* heading   = (const float*)d_in[4];
    const float* W1        = (const float*)d_in[5];
    const float* b1        = (const float*)d_in[6];
    const float* W2        = (const float*)d_in[7];
    const float* b2        = (const float*)d_in[8];
    const float* W3        = (const float*)d_in[9];
    const float* b3        = (const float*)d_in[10];
    const float* Wr        = (const float*)d_in[11];
    const float* br        = (const float*)d_in[12];
    float* out = (float*)d_out;

    char* ws = (char*)d_ws;
    float4* kp4  = (float4*)(ws);
    int*    cntw = (int*)(ws + 221184);
    int*    idxw = (int*)(ws + 276480);
    float*  F    = (float*)(ws + 1161216);
    float*  WrT  = (float*)(ws + 2209792);

    prep_k<<<dim3(PREP_NBLK), dim3(256), 0, stream>>>(
        seed_feat, W1, b1, Wr, seed_xyz, boxes, origins, heading,
        F, WrT, kp4, cntw, idxw);
    pf_k<<<dim3(512), dim3(512), 0, stream>>>(
        seed_xyz, F, W1, b2, b3, W2, W3, WrT, br, kp4, cntw, idxw, out);
}

// Round 15
// 141.571 us; speedup vs baseline: 1.1301x; 1.1301x over previous
//
#include <hip/hip_runtime.h>

#define B_ 2
#define N_ 1024
#define C_ 256
#define P_ 256
#define K_ 27
#define M_ (P_ * K_)        // 6912
#define TOTKP (B_ * M_)     // 13824
#define NS 16
#define R2C 0.04f
#define QDIM 864            // 32*K_

// ---------------- ws layout (bytes) ----------------
// kp4 : float4[TOTKP]   @ 0        (221184)
// cnt : int[TOTKP]      @ 221184   (55296)
// idx : int[TOTKP*16]   @ 276480   (884736)
// F   : float[B*N*128]  @ 1161216  (1048576)
// WrT : float[864*128]  @ 2209792  (442368)   total ~2.65 MB

// prep_k blockIdx ranges
#define PREP_WRT0    256      // 108 blocks
#define PREP_BALLQ0  364      // 3456 blocks
#define PREP_NBLK    3820

// ---------- kernel 1: fused prep = fpre + WrT transpose + ball query ----------
__global__ __launch_bounds__(256) void prep_k(
    const float* __restrict__ sf, const float* __restrict__ W1,
    const float* __restrict__ b1, const float* __restrict__ Wr,
    const float* __restrict__ seed_xyz, const float* __restrict__ boxes,
    const float* __restrict__ origins, const float* __restrict__ heading,
    float* __restrict__ F, float* __restrict__ WrT,
    float4* __restrict__ kp4, int* __restrict__ cntw, int* __restrict__ idxw)
{
    __shared__ __align__(16) float ssf[C_ * 8];
    int tid = threadIdx.x;
    int bid = blockIdx.x;

    if (bid < PREP_WRT0) {
        // ---- task A: F'[b,n,j] = b1[j] + sum_c sf[b,c,n]*W1[3+c,j] ----
        int b = bid >> 7;
        int n0 = (bid & 127) * 8;
        for (int e = tid; e < C_ * 8; e += 256) {
            int c = e >> 3, i = e & 7;
            ssf[e] = sf[(b * C_ + c) * N_ + n0 + i];
        }
        __syncthreads();
        int j = tid & 127;
        int h = tid >> 7;               // 4-seed half
        float acc[4];
        float bj = b1[j];
#pragma unroll
        for (int i = 0; i < 4; i++) acc[i] = bj;
#pragma unroll 8
        for (int c = 0; c < C_; ++c) {
            float w = W1[(3 + c) * 128 + j];
            float4 s = *(const float4*)&ssf[c * 8 + h * 4];
            acc[0] = fmaf(s.x, w, acc[0]);
            acc[1] = fmaf(s.y, w, acc[1]);
            acc[2] = fmaf(s.z, w, acc[2]);
            acc[3] = fmaf(s.w, w, acc[3]);
        }
#pragma unroll
        for (int i = 0; i < 4; i++)
            F[(b * N_ + n0 + h * 4 + i) * 128 + j] = acc[i];
    } else if (bid < PREP_BALLQ0) {
        // ---- task B: WrT[q][j] = Wr[j][q], float4 reads ----
        int e4 = (bid - PREP_WRT0) * 256 + tid;       // < 27648
        int j = e4 / 216, qq = e4 - j * 216;
        float4 v = ((const float4*)(Wr + j * QDIM))[qq];
        int q0 = qq * 4;
        WrT[(q0 + 0) * 128 + j] = v.x;
        WrT[(q0 + 1) * 128 + j] = v.y;
        WrT[(q0 + 2) * 128 + j] = v.z;
        WrT[(q0 + 3) * 128 + j] = v.w;
    } else {
        // ---- task C: keypoints + ball query (wave per keypoint) ----
        int wid = tid >> 6, lane = tid & 63;
        int kpg = (bid - PREP_BALLQ0) * 4 + wid;
        int b = kpg / M_;
        int m = kpg - b * M_;
        int p = m / K_, a = m - p * K_;

        const float* bx = boxes + (b * P_ + p) * 6;
        const float* og = origins + (b * P_ + p) * 3;
        float th = heading[b * P_ + p];
        float di = (float)(a / 9), dj = (float)((a / 3) % 3), dk = (float)(a % 3);
        float s0 = __fadd_rn(bx[0], bx[3]);
        float s1 = __fadd_rn(bx[1], bx[4]);
        float s2 = __fadd_rn(bx[2], bx[5]);
        float lx = __fsub_rn(__fmul_rn(__fdiv_rn(__fadd_rn(di, 0.5f), 3.0f), s0), bx[0]);
        float ly = __fsub_rn(__fmul_rn(__fdiv_rn(__fadd_rn(dj, 0.5f), 3.0f), s1), bx[1]);
        float lz = __fsub_rn(__fmul_rn(__fdiv_rn(__fadd_rn(dk, 0.5f), 3.0f), s2), bx[2]);
        float ct = cosf(th), st = sinf(th);
        float kx = __fadd_rn(__fadd_rn(__fmul_rn(lx, ct), __fmul_rn(ly, st)), og[0]);
        float ky = __fadd_rn(__fadd_rn(__fmul_rn(lx, -st), __fmul_rn(ly, ct)), og[1]);
        float kz = __fadd_rn(lz, og[2]);
        if (lane == 0) kp4[kpg] = make_float4(kx, ky, kz, 0.f);
        float kk = __fadd_rn(__fadd_rn(__fmul_rn(kx, kx), __fmul_rn(ky, ky)),
                             __fmul_rn(kz, kz));

        const float* sb = seed_xyz + b * (N_ * 3) + lane * 48;
        float f[48];
#pragma unroll
        for (int q = 0; q < 12; q++)
            ((float4*)f)[q] = ((const float4*)sb)[q];

        unsigned mask = 0;
#pragma unroll
        for (int i = 0; i < 16; i++) {
            float x = f[3 * i], y = f[3 * i + 1], z = f[3 * i + 2];
            float ss = __fadd_rn(__fadd_rn(__fmul_rn(x, x), __fmul_rn(y, y)),
                                 __fmul_rn(z, z));
            float dot = __fadd_rn(__fadd_rn(__fmul_rn(kx, x), __fmul_rn(ky, y)),
                                  __fmul_rn(kz, z));
            float d2 = __fsub_rn(__fadd_rn(kk, ss), __fmul_rn(2.0f, dot));
            mask |= (d2 < R2C ? 1u : 0u) << i;
        }

        int pc = __popc(mask);
        int incl = pc;
#pragma unroll
        for (int d = 1; d < 64; d <<= 1) {
            int v = __shfl_up(incl, d);
            if (lane >= d) incl += v;
        }
        int total = __shfl(incl, 63);
        int base = incl - pc;

        int* ip = idxw + kpg * NS;
        unsigned mm = mask;
        while (mm && base < NS) {
            int i = __ffs(mm) - 1;
            mm &= mm - 1;
            ip[base++] = lane * 16 + i;
        }
        if (lane == 0) cntw[kpg] = total < NS ? total : NS;
    }
}

// ---------- kernel 2: per-box worklist MLP + atomic maxpool + GEMM ----------
// one block of 256 threads (4 waves) per (b,p) box. launch_bounds matches the
// measured-clean R11 config (88 VGPR, no scratch); do NOT tighten to (.,4) —
// that clamped VGPRs to 64 and spilled ~70 MB to scratch (R13 counters).
__global__ __launch_bounds__(256, 2) void pf_k(
    const float* __restrict__ seed_xyz, const float* __restrict__ F,
    const float* __restrict__ W1, const float* __restrict__ b2g,
    const float* __restrict__ b3g, const float* __restrict__ W2g,
    const float* __restrict__ W3g, const float* __restrict__ WrT,
    const float* __restrict__ br, const float4* __restrict__ kp4,
    const int* __restrict__ cntw, const int* __restrict__ idxw,
    float* __restrict__ out)
{
    __shared__ __align__(16) float sW2[128 * 64];      // 32 KB
    __shared__ __align__(16) float sW3[64 * 32];       // 8 KB
    __shared__ __align__(16) float sH1[4 * 4 * 128];   // 8 KB
    __shared__ __align__(16) float sH2[4 * 4 * 64];    // 4 KB
    __shared__ __align__(16) int   ft_i[QDIM];         // 3.4 KB
    __shared__ __align__(16) int   swl[K_ * NS];       // 1.7 KB worklist (k<<16)|n
    __shared__ __align__(16) float4 skp[K_];
    __shared__ int scnt[K_], koff[K_], sS;
    __shared__ __align__(16) float pj[128];

    int tid = threadIdx.x;
    int wid = tid >> 6, lane = tid & 63;
    int bp = blockIdx.x;              // 0..511
    int b = bp >> 8, p = bp & 255;

    // ---- stage weights, metadata; zero ft ----
    for (int e = tid; e < 2048; e += 256)
        ((float4*)sW2)[e] = ((const float4*)W2g)[e];
    for (int e = tid; e < 512; e += 256)
        ((float4*)sW3)[e] = ((const float4*)W3g)[e];
    for (int e = tid; e < QDIM; e += 256)
        ft_i[e] = 0;
    if (tid < K_) {
        int kpg = bp * K_ + tid;
        scnt[tid] = cntw[kpg];
        skp[tid] = kp4[kpg];
    }
    __syncthreads();

    // ---- wave 0: exclusive scan of per-keypoint list counts (lc = max(cnt,1)) ----
    if (wid == 0) {
        int lc = 0;
        if (lane < K_) {
            int cc = scnt[lane];
            lc = cc > 0 ? cc : 1;
        }
        int incl = lc;
#pragma unroll
        for (int d = 1; d < 32; d <<= 1) {
            int v = __shfl_up(incl, d);
            if (lane >= d) incl += v;
        }
        if (lane < K_) koff[lane] = incl - lc;
        if (lane == K_ - 1) sS = incl;
    }
    __syncthreads();

    // ---- fill worklist ----
    for (int e = tid; e < K_ * NS; e += 256) {
        int k = e >> 4, s = e & 15;
        int cc = scnt[k];
        int lc = cc > 0 ? cc : 1;
        if (s < lc) {
            int n = (s < cc) ? idxw[(bp * K_ + k) * NS + s] : 0;
            swl[koff[k] + s] = (k << 16) | n;
        }
    }
    __syncthreads();

    int S = sS;
    int G = (S + 3) >> 2;

    // per-lane constants
    float w1x0 = W1[lane],        w1x1 = W1[lane + 64];
    float w1y0 = W1[128 + lane],  w1y1 = W1[128 + lane + 64];
    float w1z0 = W1[256 + lane],  w1z1 = W1[256 + lane + 64];
    float b2j = b2g[lane];
    float b3t = b3g[lane & 31];
    int jh = lane >> 5;
    int t = lane & 31;
    float* myH1 = sH1 + wid * 4 * 128;
    float* myH2 = sH2 + wid * 4 * 64;

    // ---- phase A: GS=4 groups over the worklist, wave-strided ----
    for (int g = wid; g < G; g += 4) {
        int kk4[4], nn[4];
        float gx[4], gy[4], gz[4];
#pragma unroll
        for (int u = 0; u < 4; u++) {
            int e = 4 * g + u; if (e >= S) e = S - 1;
            int w = swl[e];
            int k = w >> 16, n = w & 0xffff;
            kk4[u] = k; nn[u] = n;
            float4 kp = skp[k];
            const float* sp = seed_xyz + (b * N_ + n) * 3;
            gx[u] = __fdiv_rn(__fsub_rn(sp[0], kp.x), 0.2f);
            gy[u] = __fdiv_rn(__fsub_rn(sp[1], kp.y), 0.2f);
            gz[u] = __fdiv_rn(__fsub_rn(sp[2], kp.z), 0.2f);
        }
#pragma unroll
        for (int u = 0; u < 4; u++) {
            const float* fp = F + (b * N_ + nn[u]) * 128;
            float v0 = fp[lane];
            float v1 = fp[lane + 64];
            v0 = fmaf(gx[u], w1x0, fmaf(gy[u], w1y0, fmaf(gz[u], w1z0, v0)));
            v1 = fmaf(gx[u], w1x1, fmaf(gy[u], w1y1, fmaf(gz[u], w1z1, v1)));
            myH1[u * 128 + lane] = fmaxf(v0, 0.f);
            myH1[u * 128 + lane + 64] = fmaxf(v1, 0.f);
        }
        float acc[4];
#pragma unroll
        for (int u = 0; u < 4; u++) acc[u] = b2j;
#pragma unroll
        for (int cc = 0; cc < 128; cc += 4) {
            float w0 = sW2[(cc + 0) * 64 + lane];
            float w1 = sW2[(cc + 1) * 64 + lane];
            float w2 = sW2[(cc + 2) * 64 + lane];
            float w3 = sW2[(cc + 3) * 64 + lane];
#pragma unroll
            for (int u = 0; u < 4; u++) {
                float4 h = *(const float4*)&myH1[u * 128 + cc];
                acc[u] = fmaf(h.x, w0, fmaf(h.y, w1, fmaf(h.z, w2, fmaf(h.w, w3, acc[u]))));
            }
        }
#pragma unroll
        for (int u = 0; u < 4; u++) myH2[u * 64 + lane] = fmaxf(acc[u], 0.f);
        float a3[4];
#pragma unroll
        for (int u = 0; u < 4; u++) a3[u] = (jh == 0) ? b3t : 0.f;
#pragma unroll
        for (int jj = 0; jj < 32; jj += 4) {
            int j0 = jh * 32 + jj;
            float w0 = sW3[(j0 + 0) * 32 + t];
            float w1 = sW3[(j0 + 1) * 32 + t];
            float w2 = sW3[(j0 + 2) * 32 + t];
            float w3 = sW3[(j0 + 3) * 32 + t];
#pragma unroll
            for (int u = 0; u < 4; u++) {
                float4 h = *(const float4*)&myH2[u * 64 + j0];
                a3[u] = fmaf(h.x, w0, fmaf(h.y, w1, fmaf(h.z, w2, fmaf(h.w, w3, a3[u]))));
            }
        }
#pragma unroll
        for (int u = 0; u < 4; u++) {
            float v = a3[u] + __shfl_xor(a3[u], 32);
            int vi = __float_as_int(fmaxf(v, 0.f));
            if (lane < 32) atomicMax(&ft_i[t * K_ + kk4[u]], vi);
        }
    }
    __syncthreads();

    // ---- phase B: out[b,j,p] = br[j] + sum_q ft[q]*WrT[q,j]  (2-way K split) ----
    int j = tid & 127;
    int h = tid >> 7;                 // 0..1, q range [h*432, h*432+432)
    float a = 0.f;
    const int* fq = ft_i + h * 432;
    const float* wq = WrT + (h * 432) * 128 + j;
#pragma unroll 4
    for (int q = 0; q < 432; ++q)
        a = fmaf(__int_as_float(fq[q]), wq[q * 128], a);
    if (h == 1) pj[j] = a;
    __syncthreads();
    if (h == 0)
        out[(b * 128 + j) * 256 + p] = a + pj[j] + br[j];
}

extern "C" void kernel_launch(void* const* d_in, const int* in_sizes, int n_in,
                              void* d_out, int out_size, void* d_ws, size_t ws_size,
                              hipStream_t stream)
{
    const float* seed_xyz  = (const float*)d_in[0];
    const float* seed_feat = (const float*)d_in[1];
    const float* boxes     = (const float*)d_in[2];
    const float* origins   = (const float*)d_in[3];
    const float* heading   = (const float*)d_in[4];
    const float* W1        = (const float*)d_in[5];
    const float* b1        = (const float*)d_in[6];
    const float* W2        = (const float*)d_in[7];
    const float* b2        = (const float*)d_in[8];
    const float* W3        = (const float*)d_in[9];
    const float* b3        = (const float*)d_in[10];
    const float* Wr        = (const float*)d_in[11];
    const float* br        = (const float*)d_in[12];
    float* out = (float*)d_out;

    char* ws = (char*)d_ws;
    float4* kp4  = (float4*)(ws);
    int*    cntw = (int*)(ws + 221184);
    int*    idxw = (int*)(ws + 276480);
    float*  F    = (float*)(ws + 1161216);
    float*  WrT  = (float*)(ws + 2209792);

    prep_k<<<dim3(PREP_NBLK), dim3(256), 0, stream>>>(
        seed_feat, W1, b1, Wr, seed_xyz, boxes, origins, heading,
        F, WrT, kp4, cntw, idxw);
    pf_k<<<dim3(512), dim3(256), 0, stream>>>(
        seed_xyz, F, W1, b2, b3, W2, W3, WrT, br, kp4, cntw, idxw, out);
}